// Round 11
// baseline (115.579 us; speedup 1.0000x reference)
//
#include <hip/hip_runtime.h>
#include <cmath>

#define B_    2
#define NQ_   11531
#define NV_   11531
#define M_    (B_ * NQ_)   // 23062

typedef unsigned short u16;
typedef unsigned int   u32;
typedef __attribute__((ext_vector_type(8))) short bf16x8;
typedef __attribute__((ext_vector_type(4))) float f32x4;

__device__ __forceinline__ u16 f2bf(float f) {
    union { float f; unsigned u; } v; v.f = f;
    unsigned r = v.u + 0x7FFFu + ((v.u >> 16) & 1u);  // RNE
    return (u16)(r >> 16);
}
__device__ __forceinline__ float lo_bf(u32 u) {
    union { unsigned u; float f; } v; v.u = u << 16; return v.f;
}
__device__ __forceinline__ float hi_bf(u32 u) {
    union { unsigned u; float f; } v; v.u = u & 0xFFFF0000u; return v.f;
}

// Sort key: 32x32 quantization of the level-0 reference point (+ batch bit).
__device__ __forceinline__ int sort_key(const float* __restrict__ refp, int bq) {
    const int b = bq / NQ_;
    const float2 r = *(const float2*)&refp[(size_t)bq * 8];   // l=0
    int qx = (int)(r.x * 32.f); qx = min(max(qx, 0), 31);
    int qy = (int)(r.y * 32.f); qy = min(max(qy, 0), 31);
    return b * 1024 + qy * 32 + qx;
}

// ---------------------------------------------------------------------------
// L1: transpose+cast 4 weight matrices (blocks 0..255) + histogram of sort
// keys (blocks 256..346). 1-D grid, 256 threads.
// ---------------------------------------------------------------------------
__global__ __launch_bounds__(256) void transpose_hist(
    const float* __restrict__ Wv, const float* __restrict__ Wo,
    const float* __restrict__ Wa, const float* __restrict__ Wu,
    const float* __restrict__ refp,
    u16* __restrict__ Tv, u16* __restrict__ Toa, u16* __restrict__ Tu,
    int* __restrict__ hist) {
    const int bid = blockIdx.x;
    if (bid >= 256) {
        const int bq = (bid - 256) * 256 + threadIdx.x;
        if (bq < M_) atomicAdd(&hist[sort_key(refp, bq)], 1);
        return;
    }
    const int z = bid >> 6;
    const float* W; u16* T; int N; int rowoff = 0;
    if (z == 0)      { W = Wv; T = Tv;  N = 256; }
    else if (z == 1) { W = Wo; T = Toa; N = 256; }
    else if (z == 2) { W = Wa; T = Toa; N = 128; rowoff = 256; }
    else             { W = Wu; T = Tu;  N = 256; }
    const int rest = bid & 63;
    const int n0 = (rest & 7) * 32, k0 = (rest >> 3) * 32;
    if (n0 >= N) return;
    __shared__ float t[32][33];
    const int c = threadIdx.x & 31, r0 = threadIdx.x >> 5;
#pragma unroll
    for (int i = 0; i < 4; ++i)
        t[r0 + i * 8][c] = W[(size_t)(k0 + r0 + i * 8) * N + n0 + c];
    __syncthreads();
#pragma unroll
    for (int i = 0; i < 4; ++i)
        T[(size_t)(rowoff + n0 + r0 + i * 8) * 256 + k0 + c] = f2bf(t[c][r0 + i * 8]);
}

// Parallel exclusive scan of 2048 bins (one 256-thread block, 8 LDS steps).
__device__ void scan_block(const int* __restrict__ hist, int* __restrict__ ofs,
                           int* part) {
    const int tid = threadIdx.x;
    const int base = tid * 8;
    int loc[8]; int s = 0;
#pragma unroll
    for (int i = 0; i < 8; ++i) { loc[i] = s; s += hist[base + i]; }
    part[tid] = s;
    __syncthreads();
    for (int d = 1; d < 256; d <<= 1) {
        const int v = part[tid];
        const int u = (tid >= d) ? part[tid - d] : 0;
        __syncthreads();
        part[tid] = v + u;
        __syncthreads();
    }
    const int off = (tid > 0) ? part[tid - 1] : 0;
#pragma unroll
    for (int i = 0; i < 8; ++i) ofs[base + i] = off + loc[i];
}

// ---------------------------------------------------------------------------
// L3: fused repack + scatter. Blocks [0, NSC): scatter perm. Blocks [NSC, ...):
// pack v3[h][r][c] = (ws_v[r][h*32+c], ws_v[r+1][h*32+c]) — one uint4/thread,
// fully coalesced reads and writes.
// ---------------------------------------------------------------------------
__global__ __launch_bounds__(256) void repack_scatter(
    const u16* __restrict__ ws_v, const float* __restrict__ refp,
    int* __restrict__ ofs, int* __restrict__ perm,
    u32* __restrict__ v3, int nsc) {
    const int bid = blockIdx.x;
    const int tid = threadIdx.x;
    if (bid < nsc) {
        const int bq = bid * 256 + tid;
        if (bq < M_) {
            const int pos = atomicAdd(&ofs[sort_key(refp, bq)], 1);
            perm[pos] = bq;
        }
        return;
    }
    const int g4 = (bid - nsc) * 256 + tid;    // uint4 index; total 8*M_*8
    if (g4 >= 8 * M_ * 8) return;
    const int h = g4 / (M_ * 8);               // head
    const int rem = g4 - h * (M_ * 8);
    const int r = rem >> 3;
    const int c = (rem & 7) * 4;
    const ushort4 lo = *(const ushort4*)&ws_v[(size_t)r * 256 + h * 32 + c];
    ushort4 hi = make_ushort4(0, 0, 0, 0);
    if (r + 1 < M_) hi = *(const ushort4*)&ws_v[(size_t)(r + 1) * 256 + h * 32 + c];
    uint4 o;
    o.x = (u32)lo.x | ((u32)hi.x << 16);
    o.y = (u32)lo.y | ((u32)hi.y << 16);
    o.z = (u32)lo.z | ((u32)hi.z << 16);
    o.w = (u32)lo.w | ((u32)hi.w << 16);
    *(uint4*)&v3[((size_t)h * M_ + r) * 32 + c] = o;
}

// ---------------------------------------------------------------------------
// bf16 MFMA GEMM body. K_STEP=64, 128x128 tile, 4 waves, 16x16x32 MFMA.
// EPI: 0 = fp32 row-major C; 1 = bf16 row-major C. Coalesced stores only.
// ---------------------------------------------------------------------------
template <int TN, bool ABF, int EPI>
__device__ __forceinline__ void gemm_body(const void* __restrict__ Av,
                                          const u16* __restrict__ WT,
                                          const float* __restrict__ bias,
                                          const float* __restrict__ bias2,
                                          void* __restrict__ Cv, int M,
                                          int bm, int bn,
                                          short* A_l, short* B_l) {
    constexpr int K = 256;
    const int tid = threadIdx.x;
    const int w = tid >> 6;
    const int lane = tid & 63;
    const int wr = (w >> 1) * 64;
    const int wc = (w & 1) * 64;
    const int lr = lane & 15;

    f32x4 acc[4][4] = {};

    for (int k0 = 0; k0 < K; k0 += 64) {
        if constexpr (!ABF) {
            const float* A = (const float*)Av;
#pragma unroll
            for (int i = 0; i < 8; ++i) {
                const int vid = tid + i * 256;
                const int ar = vid >> 4;
                const int ak = (vid & 15) * 4;
                const int gr = bm + ar;
                float4 av = make_float4(0.f, 0.f, 0.f, 0.f);
                if (gr < M) av = *(const float4*)&A[(size_t)gr * K + k0 + ak];
                ushort4 hv;
                hv.x = f2bf(av.x); hv.y = f2bf(av.y); hv.z = f2bf(av.z); hv.w = f2bf(av.w);
                *(ushort4*)&A_l[ar * 72 + ak] = hv;
            }
        } else {
            const u16* A = (const u16*)Av;
#pragma unroll
            for (int i = 0; i < 4; ++i) {
                const int vid = tid + i * 256;
                const int ar = vid >> 3;
                const int ak = (vid & 7) * 8;
                const int gr = bm + ar;
                uint4 hv = make_uint4(0u, 0u, 0u, 0u);
                if (gr < M) hv = *(const uint4*)&A[(size_t)gr * K + k0 + ak];
                *(uint4*)&A_l[ar * 72 + ak] = hv;
            }
        }
#pragma unroll
        for (int i = 0; i < 4; ++i) {
            const int vid = tid + i * 256;
            const int nr = vid >> 3;
            const int kk = (vid & 7) * 8;
            const uint4 wv = *(const uint4*)&WT[(size_t)(bn + nr) * K + k0 + kk];
            *(uint4*)&B_l[nr * 72 + kk] = wv;
        }
        __syncthreads();
#pragma unroll
        for (int half = 0; half < 2; ++half) {
            const int kg = half * 32 + (lane >> 4) * 8;
            bf16x8 af[4], bfr[4];
#pragma unroll
            for (int m = 0; m < 4; ++m)
                af[m] = *(const bf16x8*)&A_l[(wr + m * 16 + lr) * 72 + kg];
#pragma unroll
            for (int n = 0; n < 4; ++n)
                bfr[n] = *(const bf16x8*)&B_l[(wc + n * 16 + lr) * 72 + kg];
#pragma unroll
            for (int m = 0; m < 4; ++m)
#pragma unroll
                for (int n = 0; n < 4; ++n)
                    acc[m][n] = __builtin_amdgcn_mfma_f32_16x16x32_bf16(af[m], bfr[n], acc[m][n], 0, 0, 0);
        }
        __syncthreads();
    }

#pragma unroll
    for (int n = 0; n < 4; ++n) {
        const int gcol = bn + wc + n * 16 + lr;
        const float bv = (TN == 384 && gcol >= 256) ? bias2[gcol - 256] : bias[gcol];
#pragma unroll
        for (int m = 0; m < 4; ++m) {
            const int rbase = bm + wr + m * 16 + (lane >> 4) * 4;
#pragma unroll
            for (int j = 0; j < 4; ++j) {
                const int grow = rbase + j;
                if (grow < M) {
                    const float o = acc[m][n][j] + bv;
                    if constexpr (EPI == 1) ((u16*)Cv)[(size_t)grow * TN + gcol] = f2bf(o);
                    else                    ((float*)Cv)[(size_t)grow * TN + gcol] = o;
                }
            }
        }
    }
}

// L2: blocks [0,2*gy) value-projection (bf16 out); [2*gy,5*gy) query->off/attn
// (fp32, TN=384); block 5*gy runs the parallel 2048-bin scan.
__global__ __launch_bounds__(256, 4) void gemm_stage1(
    const float* __restrict__ query, const float* __restrict__ value,
    const u16* __restrict__ WT_val, const u16* __restrict__ WT_oa,
    const float* __restrict__ b_val, const float* __restrict__ b_off,
    const float* __restrict__ b_attn,
    const int* __restrict__ hist, int* __restrict__ ofs,
    u16* __restrict__ ws_v, float* __restrict__ ws_oa, int M, int gy) {
    __shared__ __align__(16) short A_l[128 * 72];
    __shared__ __align__(16) short B_l[128 * 72];
    int blk = blockIdx.x;
    if (blk == 5 * gy) {
        scan_block(hist, ofs, (int*)A_l);
    } else if (blk < 2 * gy) {
        gemm_body<256, false, 1>(value, WT_val, b_val, b_val, ws_v, M,
                                 (blk >> 1) * 128, (blk & 1) * 128, A_l, B_l);
    } else {
        blk -= 2 * gy;
        gemm_body<384, false, 0>(query, WT_oa, b_off, b_attn, ws_oa, M,
                                 (blk / 3) * 128, (blk % 3) * 128, A_l, B_l);
    }
}

__global__ __launch_bounds__(256, 4) void gemm_out(
    const u16* __restrict__ samp, const u16* __restrict__ WT_out,
    const float* __restrict__ b_out, float* __restrict__ out, int M) {
    __shared__ __align__(16) short A_l[128 * 72];
    __shared__ __align__(16) short B_l[128 * 72];
    const int blk = blockIdx.x;
    gemm_body<256, true, 0>(samp, WT_out, b_out, b_out, out, M,
                            (blk >> 1) * 128, (blk & 1) * 128, A_l, B_l);
}

// ---------------------------------------------------------------------------
// Sampler v10: pair-interleaved v3 (2 fully-used 128-B lines / point),
// register-bounded engine (#pragma unroll 2 + wrap-around prefetch),
// 512 thr / 8 sorted-adjacent queries, bijective XCD swizzle.
// ---------------------------------------------------------------------------
__global__ __launch_bounds__(512, 4) void msda_sample_v10(
    const u32* __restrict__ v3,      // [8][M_][32] pair-interleaved bf16
    const float* __restrict__ oa,    // (B*NQ, 384): 256 offsets + 128 logits
    const float* __restrict__ refp,  // (B, NQ, 4, 2)
    const int* __restrict__ perm,    // sorted query order
    u16* __restrict__ samp) {        // (B*NQ, 256) bf16
    __shared__ __align__(16) float4 s_w4[1088];  // (qi*8+h)*17 + sampi
    __shared__ __align__(8)  int2   s_i2[1088];
    __shared__ int s_bq[8];
    const int tid = threadIdx.x;

    // bijective XCD swizzle (m204): XCD k gets a contiguous span of work ids
    const int nwg = gridDim.x;
    const int qq = nwg >> 3, rr = nwg & 7;
    const int xcd = blockIdx.x & 7, pos = blockIdx.x >> 3;
    const int wg = (xcd < rr ? xcd * (qq + 1) : rr * (qq + 1) + (xcd - rr) * qq) + pos;
    const int bq0 = wg * 8;

    if (tid < 8) {
        const int q = bq0 + tid;
        s_bq[tid] = perm[q < M_ ? q : M_ - 1];
    }
    __syncthreads();

#pragma unroll
    for (int half = 0; half < 2; ++half) {
        const int s = tid + half * 512;
        const int qi = s >> 7;            // 0..7
        const int rem = s & 127;          // h*16 + l*4 + p
        const int sampi = rem & 15;
        const int l = sampi >> 2;
        const int h = rem >> 4;
        const int bq = s_bq[qi];
        const int b = bq / NQ_;

        const float logit = oa[(size_t)bq * 384 + 256 + rem];
        float mx = logit;
#pragma unroll
        for (int t = 8; t >= 1; t >>= 1) mx = fmaxf(mx, __shfl_xor(mx, t, 16));
        const float e = __expf(logit - mx);
        float sm = e;
#pragma unroll
        for (int t = 8; t >= 1; t >>= 1) sm += __shfl_xor(sm, t, 16);
        const float aw = e / sm;

        const float2 off = *(const float2*)&oa[(size_t)bq * 384 + rem * 2];
        const float2 rxy = *(const float2*)&refp[(size_t)bq * 8 + l * 2];
        const int lw = (l == 0) ? 114 : (l == 1) ? 57 : (l == 2) ? 29 : 15;
        const int lh = (l == 0) ? 76 : (l == 1) ? 38 : (l == 2) ? 19 : 10;
        const int st = (l == 0) ? 0 : (l == 1) ? 8664 : (l == 2) ? 10830 : 11381;
        const int base = b * NV_ + st;

        const float px = rxy.x * (float)lw + off.x - 0.5f;
        const float py = rxy.y * (float)lh + off.y - 0.5f;
        const float x0f = floorf(px), y0f = floorf(py);
        const int x0 = (int)x0f, y0 = (int)y0f;
        const float fx = px - x0f, fy = py - y0f;

        // x-pair weights: u32 lo = value at row xs, hi = value at row xs+1.
        float wxlo = 0.f, wxhi = 0.f;
        if (x0 >= 0 && x0 < lw)      wxlo = 1.f - fx;
        else if (x0 == -1)           wxlo = fx;        // valid x1 corner shifts to lo
        if (x0 >= 0 && x0 + 1 < lw)  wxhi = fx;
        const int xs = min(max(x0, 0), lw - 1);

        const float wy0 = (y0 >= 0 && y0 < lh) ? (1.f - fy) : 0.f;
        const float wy1 = (y0 + 1 >= 0 && y0 + 1 < lh) ? fy : 0.f;
        const int ys0 = min(max(y0, 0), lh - 1);
        const int ys1 = min(max(y0 + 1, 0), lh - 1);

        const int hrow = h * M_;
        int2 iv;
        iv.x = (hrow + base + ys0 * lw + xs) << 7;   // byte offset of 128-B row
        iv.y = (hrow + base + ys1 * lw + xs) << 7;
        float4 wv;
        wv.x = aw * wxlo * wy0; wv.y = aw * wxhi * wy0;
        wv.z = aw * wxlo * wy1; wv.w = aw * wxhi * wy1;
        const int slot = (qi * 8 + h) * 17 + sampi;
        s_w4[slot] = wv;
        s_i2[slot] = iv;
    }
    __syncthreads();

    const int qi = tid >> 6;              // 0..7, wave = query
    const int lane = tid & 63;
    const int h = lane >> 3;
    const int lcoff = (lane & 7) * 16;    // 4 ch-pairs * 4 B per lane
    const int bq = s_bq[qi];
    const int sb = (qi * 8 + h) * 17;
    const char* vb = (const char*)v3;

    float acc0 = 0.f, acc1 = 0.f, acc2 = 0.f, acc3 = 0.f;
    float4 wc = s_w4[sb];
    int2 ic = s_i2[sb];
    uint4 A0 = *(const uint4*)(vb + (u32)(ic.x + lcoff));
    uint4 A1 = *(const uint4*)(vb + (u32)(ic.y + lcoff));

#pragma unroll 2
    for (int sp = 0; sp < 16; ++sp) {
        const int nxt = (sp + 1) & 15;           // wrap: uniform code, no tail branch
        const float4 wn = s_w4[sb + nxt];
        const int2 in_ = s_i2[sb + nxt];
        const uint4 B0 = *(const uint4*)(vb + (u32)(in_.x + lcoff));
        const uint4 B1 = *(const uint4*)(vb + (u32)(in_.y + lcoff));

        acc0 = fmaf(wc.x, lo_bf(A0.x), acc0); acc0 = fmaf(wc.y, hi_bf(A0.x), acc0);
        acc0 = fmaf(wc.z, lo_bf(A1.x), acc0); acc0 = fmaf(wc.w, hi_bf(A1.x), acc0);
        acc1 = fmaf(wc.x, lo_bf(A0.y), acc1); acc1 = fmaf(wc.y, hi_bf(A0.y), acc1);
        acc1 = fmaf(wc.z, lo_bf(A1.y), acc1); acc1 = fmaf(wc.w, hi_bf(A1.y), acc1);
        acc2 = fmaf(wc.x, lo_bf(A0.z), acc2); acc2 = fmaf(wc.y, hi_bf(A0.z), acc2);
        acc2 = fmaf(wc.z, lo_bf(A1.z), acc2); acc2 = fmaf(wc.w, hi_bf(A1.z), acc2);
        acc3 = fmaf(wc.x, lo_bf(A0.w), acc3); acc3 = fmaf(wc.y, hi_bf(A0.w), acc3);
        acc3 = fmaf(wc.z, lo_bf(A1.w), acc3); acc3 = fmaf(wc.w, hi_bf(A1.w), acc3);

        wc = wn; A0 = B0; A1 = B1;
    }
    if (bq0 + qi < M_) {
        ushort4 o;
        o.x = f2bf(acc0); o.y = f2bf(acc1); o.z = f2bf(acc2); o.w = f2bf(acc3);
        *(ushort4*)&samp[(size_t)bq * 256 + (h * 32 + (lane & 7) * 4)] = o;
    }
}

// ---------------------------------------------------------------------------
extern "C" void kernel_launch(void* const* d_in, const int* in_sizes, int n_in,
                              void* d_out, int out_size, void* d_ws, size_t ws_size,
                              hipStream_t stream) {
    const float* query  = (const float*)d_in[0];
    const float* refp   = (const float*)d_in[1];
    const float* value  = (const float*)d_in[2];
    const float* W_off  = (const float*)d_in[3];
    const float* b_off  = (const float*)d_in[4];
    const float* W_attn = (const float*)d_in[5];
    const float* b_attn = (const float*)d_in[6];
    const float* W_val  = (const float*)d_in[7];
    const float* b_val  = (const float*)d_in[8];
    const float* W_out  = (const float*)d_in[9];
    const float* b_out  = (const float*)d_in[10];
    float* out = (float*)d_out;

    const int M = M_;
    // ws_v (plain bf16 value proj) doubles as ws_samp: dead after repack,
    // sampler then overwrites it with samp (stream-ordered).
    u16*   ws_v    = (u16*)d_ws;                          // M*256 bf16 (11.8 MB)
    u16*   ws_samp = ws_v;
    u32*   ws_v3   = (u32*)(ws_v + (size_t)M * 256);      // 8*M*32 u32 (23.6 MB)
    float* ws_oa   = (float*)(ws_v3 + (size_t)8 * M * 32); // M*384 f32 (35.4 MB)
    u16*   WT_val  = (u16*)(ws_oa + (size_t)M * 384);     // 256*256 bf16
    u16*   WT_oa   = WT_val + 256 * 256;                  // 384*256 bf16
    u16*   WT_out  = WT_oa + 384 * 256;                   // 256*256 bf16
    int*   hist    = (int*)(WT_out + 256 * 256);          // 2048
    int*   ofs     = hist + 2048;                         // 2048
    int*   perm    = ofs + 2048;                          // M

    const int gy = (M + 127) / 128;  // 181
    const int gq = (M + 255) / 256;  // 91
    const int grep = (8 * M * 8 + 255) / 256;  // 5766 repack blocks

    hipMemsetAsync(hist, 0, 2048 * sizeof(int), stream);
    transpose_hist<<<dim3(256 + gq), 256, 0, stream>>>(W_val, W_off, W_attn, W_out,
                                                       refp, WT_val, WT_oa, WT_out, hist);
    gemm_stage1<<<dim3(5 * gy + 1), 256, 0, stream>>>(query, value, WT_val, WT_oa,
                                                      b_val, b_off, b_attn,
                                                      hist, ofs, ws_v, ws_oa, M, gy);
    repack_scatter<<<dim3(gq + grep), 256, 0, stream>>>(ws_v, refp, ofs, perm,
                                                        ws_v3, gq);
    msda_sample_v10<<<dim3((M + 7) / 8), 512, 0, stream>>>(ws_v3, ws_oa, refp, perm, ws_samp);
    gemm_out<<<dim3(2 * gy), 256, 0, stream>>>(ws_samp, WT_out, b_out, out, M);
}

// Round 12
// 113.690 us; speedup vs baseline: 1.0166x; 1.0166x over previous
//
#include <hip/hip_runtime.h>
#include <cmath>

#define B_    2
#define NQ_   11531
#define NV_   11531
#define M_    (B_ * NQ_)   // 23062
#define NCB_  2883         // cast blocks per tensor: ceil(M*256 / (256*8))

typedef unsigned short u16;
typedef unsigned int   u32;
typedef __attribute__((ext_vector_type(8))) short bf16x8;
typedef __attribute__((ext_vector_type(4))) float f32x4;

__device__ __forceinline__ u16 f2bf(float f) {
    union { float f; unsigned u; } v; v.f = f;
    unsigned r = v.u + 0x7FFFu + ((v.u >> 16) & 1u);  // RNE
    return (u16)(r >> 16);
}
__device__ __forceinline__ float lo_bf(u32 u) {
    union { unsigned u; float f; } v; v.u = u << 16; return v.f;
}
__device__ __forceinline__ float hi_bf(u32 u) {
    union { unsigned u; float f; } v; v.u = u & 0xFFFF0000u; return v.f;
}

// Sort key: 32x32 quantization of the level-0 reference point (+ batch bit).
__device__ __forceinline__ int sort_key(const float* __restrict__ refp, int bq) {
    const int b = bq / NQ_;
    const float2 r = *(const float2*)&refp[(size_t)bq * 8];   // l=0
    int qx = (int)(r.x * 32.f); qx = min(max(qx, 0), 31);
    int qy = (int)(r.y * 32.f); qy = min(max(qy, 0), 31);
    return b * 1024 + qy * 32 + qx;
}

// ---------------------------------------------------------------------------
// L1: transpose+cast weights (blocks 0..255) + sort-key histogram (256..346)
// + fp32->bf16 pre-cast of query (347..347+NCB) and value (next NCB blocks).
// ---------------------------------------------------------------------------
__global__ __launch_bounds__(256) void transpose_hist_cast(
    const float* __restrict__ Wv, const float* __restrict__ Wo,
    const float* __restrict__ Wa, const float* __restrict__ Wu,
    const float* __restrict__ refp,
    const float* __restrict__ query, const float* __restrict__ value,
    u16* __restrict__ Tv, u16* __restrict__ Toa, u16* __restrict__ Tu,
    int* __restrict__ hist, u16* __restrict__ qbf, u16* __restrict__ vbf) {
    const int bid = blockIdx.x;
    const int tid = threadIdx.x;
    if (bid >= 347) {                       // streaming bf16 cast, 8 elems/thread
        const int t8 = bid - 347;
        const bool isq = t8 < NCB_;
        const int cb = isq ? t8 : t8 - NCB_;
        const float* S = isq ? query : value;
        u16* D = isq ? qbf : vbf;
        const size_t TOT = (size_t)M_ * 256;
        const size_t e = ((size_t)cb * 256 + tid) * 8;
        if (e + 8 <= TOT) {
            const float4 a = *(const float4*)&S[e];
            const float4 b = *(const float4*)&S[e + 4];
            ushort4 lo, hi;
            lo.x = f2bf(a.x); lo.y = f2bf(a.y); lo.z = f2bf(a.z); lo.w = f2bf(a.w);
            hi.x = f2bf(b.x); hi.y = f2bf(b.y); hi.z = f2bf(b.z); hi.w = f2bf(b.w);
            *(ushort4*)&D[e] = lo;
            *(ushort4*)&D[e + 4] = hi;
        } else {
            for (size_t i = e; i < TOT; ++i) D[i] = f2bf(S[i]);
        }
        return;
    }
    if (bid >= 256) {                       // histogram
        const int bq = (bid - 256) * 256 + tid;
        if (bq < M_) atomicAdd(&hist[sort_key(refp, bq)], 1);
        return;
    }
    const int z = bid >> 6;
    const float* W; u16* T; int N; int rowoff = 0;
    if (z == 0)      { W = Wv; T = Tv;  N = 256; }
    else if (z == 1) { W = Wo; T = Toa; N = 256; }
    else if (z == 2) { W = Wa; T = Toa; N = 128; rowoff = 256; }
    else             { W = Wu; T = Tu;  N = 256; }
    const int rest = bid & 63;
    const int n0 = (rest & 7) * 32, k0 = (rest >> 3) * 32;
    if (n0 >= N) return;
    __shared__ float t[32][33];
    const int c = tid & 31, r0 = tid >> 5;
#pragma unroll
    for (int i = 0; i < 4; ++i)
        t[r0 + i * 8][c] = W[(size_t)(k0 + r0 + i * 8) * N + n0 + c];
    __syncthreads();
#pragma unroll
    for (int i = 0; i < 4; ++i)
        T[(size_t)(rowoff + n0 + r0 + i * 8) * 256 + k0 + c] = f2bf(t[c][r0 + i * 8]);
}

// Parallel exclusive scan of 2048 bins (one 256-thread block, 8 LDS steps).
__device__ void scan_block(const int* __restrict__ hist, int* __restrict__ ofs,
                           int* part) {
    const int tid = threadIdx.x;
    const int base = tid * 8;
    int loc[8]; int s = 0;
#pragma unroll
    for (int i = 0; i < 8; ++i) { loc[i] = s; s += hist[base + i]; }
    part[tid] = s;
    __syncthreads();
    for (int d = 1; d < 256; d <<= 1) {
        const int v = part[tid];
        const int u = (tid >= d) ? part[tid - d] : 0;
        __syncthreads();
        part[tid] = v + u;
        __syncthreads();
    }
    const int off = (tid > 0) ? part[tid - 1] : 0;
#pragma unroll
    for (int i = 0; i < 8; ++i) ofs[base + i] = off + loc[i];
}

// ---------------------------------------------------------------------------
// L3: fused repack + scatter. Blocks [0, nsc): scatter perm. Rest: pack
// v3[h][r][c] = (ws_v[r][h*32+c], ws_v[r+1][h*32+c]) — one uint4/thread.
// ---------------------------------------------------------------------------
__global__ __launch_bounds__(256) void repack_scatter(
    const u16* __restrict__ ws_v, const float* __restrict__ refp,
    int* __restrict__ ofs, int* __restrict__ perm,
    u32* __restrict__ v3, int nsc) {
    const int bid = blockIdx.x;
    const int tid = threadIdx.x;
    if (bid < nsc) {
        const int bq = bid * 256 + tid;
        if (bq < M_) {
            const int pos = atomicAdd(&ofs[sort_key(refp, bq)], 1);
            perm[pos] = bq;
        }
        return;
    }
    const int g4 = (bid - nsc) * 256 + tid;    // uint4 index; total 8*M_*8
    if (g4 >= 8 * M_ * 8) return;
    const int h = g4 / (M_ * 8);               // head
    const int rem = g4 - h * (M_ * 8);
    const int r = rem >> 3;
    const int c = (rem & 7) * 4;
    const ushort4 lo = *(const ushort4*)&ws_v[(size_t)r * 256 + h * 32 + c];
    ushort4 hi = make_ushort4(0, 0, 0, 0);
    if (r + 1 < M_) hi = *(const ushort4*)&ws_v[(size_t)(r + 1) * 256 + h * 32 + c];
    uint4 o;
    o.x = (u32)lo.x | ((u32)hi.x << 16);
    o.y = (u32)lo.y | ((u32)hi.y << 16);
    o.z = (u32)lo.z | ((u32)hi.z << 16);
    o.w = (u32)lo.w | ((u32)hi.w << 16);
    *(uint4*)&v3[((size_t)h * M_ + r) * 32 + c] = o;
}

// ---------------------------------------------------------------------------
// bf16 MFMA GEMM body. K_STEP=64, 128x128 tile, 4 waves, 16x16x32 MFMA.
// A is always bf16 now. EPI: 0 = fp32 C; 1 = bf16 C. Coalesced stores.
// ---------------------------------------------------------------------------
template <int TN, int EPI>
__device__ __forceinline__ void gemm_body(const u16* __restrict__ A,
                                          const u16* __restrict__ WT,
                                          const float* __restrict__ bias,
                                          const float* __restrict__ bias2,
                                          void* __restrict__ Cv, int M,
                                          int bm, int bn,
                                          short* A_l, short* B_l) {
    constexpr int K = 256;
    const int tid = threadIdx.x;
    const int w = tid >> 6;
    const int lane = tid & 63;
    const int wr = (w >> 1) * 64;
    const int wc = (w & 1) * 64;
    const int lr = lane & 15;

    f32x4 acc[4][4] = {};

    for (int k0 = 0; k0 < K; k0 += 64) {
#pragma unroll
        for (int i = 0; i < 4; ++i) {
            const int vid = tid + i * 256;
            const int ar = vid >> 3;
            const int ak = (vid & 7) * 8;
            const int gr = bm + ar;
            uint4 hv = make_uint4(0u, 0u, 0u, 0u);
            if (gr < M) hv = *(const uint4*)&A[(size_t)gr * K + k0 + ak];
            *(uint4*)&A_l[ar * 72 + ak] = hv;
        }
#pragma unroll
        for (int i = 0; i < 4; ++i) {
            const int vid = tid + i * 256;
            const int nr = vid >> 3;
            const int kk = (vid & 7) * 8;
            const uint4 wv = *(const uint4*)&WT[(size_t)(bn + nr) * K + k0 + kk];
            *(uint4*)&B_l[nr * 72 + kk] = wv;
        }
        __syncthreads();
#pragma unroll
        for (int half = 0; half < 2; ++half) {
            const int kg = half * 32 + (lane >> 4) * 8;
            bf16x8 af[4], bfr[4];
#pragma unroll
            for (int m = 0; m < 4; ++m)
                af[m] = *(const bf16x8*)&A_l[(wr + m * 16 + lr) * 72 + kg];
#pragma unroll
            for (int n = 0; n < 4; ++n)
                bfr[n] = *(const bf16x8*)&B_l[(wc + n * 16 + lr) * 72 + kg];
#pragma unroll
            for (int m = 0; m < 4; ++m)
#pragma unroll
                for (int n = 0; n < 4; ++n)
                    acc[m][n] = __builtin_amdgcn_mfma_f32_16x16x32_bf16(af[m], bfr[n], acc[m][n], 0, 0, 0);
        }
        __syncthreads();
    }

#pragma unroll
    for (int n = 0; n < 4; ++n) {
        const int gcol = bn + wc + n * 16 + lr;
        const float bv = (TN == 384 && gcol >= 256) ? bias2[gcol - 256] : bias[gcol];
#pragma unroll
        for (int m = 0; m < 4; ++m) {
            const int rbase = bm + wr + m * 16 + (lane >> 4) * 4;
#pragma unroll
            for (int j = 0; j < 4; ++j) {
                const int grow = rbase + j;
                if (grow < M) {
                    const float o = acc[m][n][j] + bv;
                    if constexpr (EPI == 1) ((u16*)Cv)[(size_t)grow * TN + gcol] = f2bf(o);
                    else                    ((float*)Cv)[(size_t)grow * TN + gcol] = o;
                }
            }
        }
    }
}

// L2: blocks [0,2*gy) value-projection (vbf -> bf16 ws_v); [2*gy,5*gy)
// qbf -> off/attn (fp32, TN=384); block 5*gy runs the parallel scan.
__global__ __launch_bounds__(256, 4) void gemm_stage1(
    const u16* __restrict__ qbf, const u16* __restrict__ vbf,
    const u16* __restrict__ WT_val, const u16* __restrict__ WT_oa,
    const float* __restrict__ b_val, const float* __restrict__ b_off,
    const float* __restrict__ b_attn,
    const int* __restrict__ hist, int* __restrict__ ofs,
    u16* __restrict__ ws_v, float* __restrict__ ws_oa, int M, int gy) {
    __shared__ __align__(16) short A_l[128 * 72];
    __shared__ __align__(16) short B_l[128 * 72];
    int blk = blockIdx.x;
    if (blk == 5 * gy) {
        scan_block(hist, ofs, (int*)A_l);
    } else if (blk < 2 * gy) {
        gemm_body<256, 1>(vbf, WT_val, b_val, b_val, ws_v, M,
                          (blk >> 1) * 128, (blk & 1) * 128, A_l, B_l);
    } else {
        blk -= 2 * gy;
        gemm_body<384, 0>(qbf, WT_oa, b_off, b_attn, ws_oa, M,
                          (blk / 3) * 128, (blk % 3) * 128, A_l, B_l);
    }
}

__global__ __launch_bounds__(256, 4) void gemm_out(
    const u16* __restrict__ samp, const u16* __restrict__ WT_out,
    const float* __restrict__ b_out, float* __restrict__ out, int M) {
    __shared__ __align__(16) short A_l[128 * 72];
    __shared__ __align__(16) short B_l[128 * 72];
    const int blk = blockIdx.x;
    gemm_body<256, 0>(samp, WT_out, b_out, b_out, out, M,
                      (blk >> 1) * 128, (blk & 1) * 128, A_l, B_l);
}

// ---------------------------------------------------------------------------
// Sampler v10: pair-interleaved v3 (2 fully-used 128-B lines / point),
// register-bounded engine (#pragma unroll 2 + wrap-around prefetch),
// 512 thr / 8 sorted-adjacent queries, bijective XCD swizzle.
// ---------------------------------------------------------------------------
__global__ __launch_bounds__(512, 4) void msda_sample_v10(
    const u32* __restrict__ v3,      // [8][M_][32] pair-interleaved bf16
    const float* __restrict__ oa,    // (B*NQ, 384): 256 offsets + 128 logits
    const float* __restrict__ refp,  // (B, NQ, 4, 2)
    const int* __restrict__ perm,    // sorted query order
    u16* __restrict__ samp) {        // (B*NQ, 256) bf16
    __shared__ __align__(16) float4 s_w4[1088];  // (qi*8+h)*17 + sampi
    __shared__ __align__(8)  int2   s_i2[1088];
    __shared__ int s_bq[8];
    const int tid = threadIdx.x;

    // bijective XCD swizzle (m204): XCD k gets a contiguous span of work ids
    const int nwg = gridDim.x;
    const int qq = nwg >> 3, rr = nwg & 7;
    const int xcd = blockIdx.x & 7, pos = blockIdx.x >> 3;
    const int wg = (xcd < rr ? xcd * (qq + 1) : rr * (qq + 1) + (xcd - rr) * qq) + pos;
    const int bq0 = wg * 8;

    if (tid < 8) {
        const int q = bq0 + tid;
        s_bq[tid] = perm[q < M_ ? q : M_ - 1];
    }
    __syncthreads();

#pragma unroll
    for (int half = 0; half < 2; ++half) {
        const int s = tid + half * 512;
        const int qi = s >> 7;            // 0..7
        const int rem = s & 127;          // h*16 + l*4 + p
        const int sampi = rem & 15;
        const int l = sampi >> 2;
        const int h = rem >> 4;
        const int bq = s_bq[qi];
        const int b = bq / NQ_;

        const float logit = oa[(size_t)bq * 384 + 256 + rem];
        float mx = logit;
#pragma unroll
        for (int t = 8; t >= 1; t >>= 1) mx = fmaxf(mx, __shfl_xor(mx, t, 16));
        const float e = __expf(logit - mx);
        float sm = e;
#pragma unroll
        for (int t = 8; t >= 1; t >>= 1) sm += __shfl_xor(sm, t, 16);
        const float aw = e / sm;

        const float2 off = *(const float2*)&oa[(size_t)bq * 384 + rem * 2];
        const float2 rxy = *(const float2*)&refp[(size_t)bq * 8 + l * 2];
        const int lw = (l == 0) ? 114 : (l == 1) ? 57 : (l == 2) ? 29 : 15;
        const int lh = (l == 0) ? 76 : (l == 1) ? 38 : (l == 2) ? 19 : 10;
        const int st = (l == 0) ? 0 : (l == 1) ? 8664 : (l == 2) ? 10830 : 11381;
        const int base = b * NV_ + st;

        const float px = rxy.x * (float)lw + off.x - 0.5f;
        const float py = rxy.y * (float)lh + off.y - 0.5f;
        const float x0f = floorf(px), y0f = floorf(py);
        const int x0 = (int)x0f, y0 = (int)y0f;
        const float fx = px - x0f, fy = py - y0f;

        // x-pair weights: u32 lo = value at row xs, hi = value at row xs+1.
        float wxlo = 0.f, wxhi = 0.f;
        if (x0 >= 0 && x0 < lw)      wxlo = 1.f - fx;
        else if (x0 == -1)           wxlo = fx;        // valid x1 corner shifts to lo
        if (x0 >= 0 && x0 + 1 < lw)  wxhi = fx;
        const int xs = min(max(x0, 0), lw - 1);

        const float wy0 = (y0 >= 0 && y0 < lh) ? (1.f - fy) : 0.f;
        const float wy1 = (y0 + 1 >= 0 && y0 + 1 < lh) ? fy : 0.f;
        const int ys0 = min(max(y0, 0), lh - 1);
        const int ys1 = min(max(y0 + 1, 0), lh - 1);

        const int hrow = h * M_;
        int2 iv;
        iv.x = (hrow + base + ys0 * lw + xs) << 7;   // byte offset of 128-B row
        iv.y = (hrow + base + ys1 * lw + xs) << 7;
        float4 wv;
        wv.x = aw * wxlo * wy0; wv.y = aw * wxhi * wy0;
        wv.z = aw * wxlo * wy1; wv.w = aw * wxhi * wy1;
        const int slot = (qi * 8 + h) * 17 + sampi;
        s_w4[slot] = wv;
        s_i2[slot] = iv;
    }
    __syncthreads();

    const int qi = tid >> 6;              // 0..7, wave = query
    const int lane = tid & 63;
    const int h = lane >> 3;
    const int lcoff = (lane & 7) * 16;    // 4 ch-pairs * 4 B per lane
    const int bq = s_bq[qi];
    const int sb = (qi * 8 + h) * 17;
    const char* vb = (const char*)v3;

    float acc0 = 0.f, acc1 = 0.f, acc2 = 0.f, acc3 = 0.f;
    float4 wc = s_w4[sb];
    int2 ic = s_i2[sb];
    uint4 A0 = *(const uint4*)(vb + (u32)(ic.x + lcoff));
    uint4 A1 = *(const uint4*)(vb + (u32)(ic.y + lcoff));

#pragma unroll 2
    for (int sp = 0; sp < 16; ++sp) {
        const int nxt = (sp + 1) & 15;           // wrap: uniform code, no tail branch
        const float4 wn = s_w4[sb + nxt];
        const int2 in_ = s_i2[sb + nxt];
        const uint4 B0 = *(const uint4*)(vb + (u32)(in_.x + lcoff));
        const uint4 B1 = *(const uint4*)(vb + (u32)(in_.y + lcoff));

        acc0 = fmaf(wc.x, lo_bf(A0.x), acc0); acc0 = fmaf(wc.y, hi_bf(A0.x), acc0);
        acc0 = fmaf(wc.z, lo_bf(A1.x), acc0); acc0 = fmaf(wc.w, hi_bf(A1.x), acc0);
        acc1 = fmaf(wc.x, lo_bf(A0.y), acc1); acc1 = fmaf(wc.y, hi_bf(A0.y), acc1);
        acc1 = fmaf(wc.z, lo_bf(A1.y), acc1); acc1 = fmaf(wc.w, hi_bf(A1.y), acc1);
        acc2 = fmaf(wc.x, lo_bf(A0.z), acc2); acc2 = fmaf(wc.y, hi_bf(A0.z), acc2);
        acc2 = fmaf(wc.z, lo_bf(A1.z), acc2); acc2 = fmaf(wc.w, hi_bf(A1.z), acc2);
        acc3 = fmaf(wc.x, lo_bf(A0.w), acc3); acc3 = fmaf(wc.y, hi_bf(A0.w), acc3);
        acc3 = fmaf(wc.z, lo_bf(A1.w), acc3); acc3 = fmaf(wc.w, hi_bf(A1.w), acc3);

        wc = wn; A0 = B0; A1 = B1;
    }
    if (bq0 + qi < M_) {
        ushort4 o;
        o.x = f2bf(acc0); o.y = f2bf(acc1); o.z = f2bf(acc2); o.w = f2bf(acc3);
        *(ushort4*)&samp[(size_t)bq * 256 + (h * 32 + (lane & 7) * 4)] = o;
    }
}

// ---------------------------------------------------------------------------
extern "C" void kernel_launch(void* const* d_in, const int* in_sizes, int n_in,
                              void* d_out, int out_size, void* d_ws, size_t ws_size,
                              hipStream_t stream) {
    const float* query  = (const float*)d_in[0];
    const float* refp   = (const float*)d_in[1];
    const float* value  = (const float*)d_in[2];
    const float* W_off  = (const float*)d_in[3];
    const float* b_off  = (const float*)d_in[4];
    const float* W_attn = (const float*)d_in[5];
    const float* b_attn = (const float*)d_in[6];
    const float* W_val  = (const float*)d_in[7];
    const float* b_val  = (const float*)d_in[8];
    const float* W_out  = (const float*)d_in[9];
    const float* b_out  = (const float*)d_in[10];
    float* out = (float*)d_out;

    const int M = M_;
    // Aliasing plan (stream-ordered, no intra-dispatch hazards):
    //   ws_v  : value proj bf16; dead after repack; reused as samp.
    //   ws_v3 : repack target; its first 11.8 MB doubles as vbf, which is
    //           consumed by gemm_stage1 BEFORE repack overwrites the region.
    u16*   ws_v    = (u16*)d_ws;                            // M*256 bf16
    u16*   ws_samp = ws_v;
    u32*   ws_v3   = (u32*)(ws_v + (size_t)M * 256);        // 8*M*32 u32
    u16*   vbf     = (u16*)ws_v3;                           // M*256 bf16 (alias)
    float* ws_oa   = (float*)(ws_v3 + (size_t)8 * M * 32);  // M*384 f32
    u16*   qbf     = (u16*)(ws_oa + (size_t)M * 384);       // M*256 bf16
    u16*   WT_val  = qbf + (size_t)M * 256;                 // 256*256 bf16
    u16*   WT_oa   = WT_val + 256 * 256;                    // 384*256 bf16
    u16*   WT_out  = WT_oa + 384 * 256;                     // 256*256 bf16
    int*   hist    = (int*)(WT_out + 256 * 256);            // 2048
    int*   ofs     = hist + 2048;                           // 2048
    int*   perm    = ofs + 2048;                            // M

    const int gy = (M + 127) / 128;  // 181
    const int gq = (M + 255) / 256;  // 91
    const int grep = (8 * M * 8 + 255) / 256;  // 5766 repack blocks

    hipMemsetAsync(hist, 0, 2048 * sizeof(int), stream);
    transpose_hist_cast<<<dim3(347 + 2 * NCB_), 256, 0, stream>>>(
        W_val, W_off, W_attn, W_out, refp, query, value,
        WT_val, WT_oa, WT_out, hist, qbf, vbf);
    gemm_stage1<<<dim3(5 * gy + 1), 256, 0, stream>>>(qbf, vbf, WT_val, WT_oa,
                                                      b_val, b_off, b_attn,
                                                      hist, ofs, ws_v, ws_oa, M, gy);
    repack_scatter<<<dim3(gq + grep), 256, 0, stream>>>(ws_v, refp, ofs, perm,
                                                        ws_v3, gq);
    msda_sample_v10<<<dim3((M + 7) / 8), 512, 0, stream>>>(ws_v3, ws_oa, refp, perm, ws_samp);
    gemm_out<<<dim3(2 * gy), 256, 0, stream>>>(ws_samp, WT_out, b_out, out, M);
}